// Round 11
// baseline (442.685 us; speedup 1.0000x reference)
//
#include <hip/hip_runtime.h>

#define D 64
#define K 5
#define LK 8                  // per-lane / per-wave candidate list length
#define GK 12                 // global candidates rescored per row
#define NW 8                  // waves per select block
#define NTILES 625            // 10000 / 16 exactly
#define PREPBLK 352           // covers 90112 >= 80000 repack + 10000 norm threads
typedef unsigned int u32;
typedef unsigned long long u64;
typedef __bf16 bf16x8 __attribute__((ext_vector_type(8)));
typedef float  f32x4v __attribute__((ext_vector_type(4)));

// v_med3_u32 (GCN3+; no HIP builtin)
__device__ __forceinline__ u32 med3u(u32 a, u32 b, u32 c) {
    u32 r;
    asm("v_med3_u32 %0, %1, %2, %3" : "=v"(r) : "v"(a), "v"(b), "v"(c));
    return r;
}

// ---- u32 key: [31:14] = top bits of FULL monotone fp32 map, [13:0] = 0x3FFF-idx
// (== (~idx)&0x3FFF for idx<16384). bigger key == (bigger value, then lower idx).
__device__ __forceinline__ int idx32(u32 key) { return (int)((~key) & 0x3FFFu); }

// exact final key (value, then lower idx)
__device__ __forceinline__ u64 packKV(float v, int idx) {
    u32 u = __float_as_uint(v);
    u ^= ((u32)((int)u >> 31)) | 0x80000000u;
    return ((u64)u << 32) | (u32)(~idx);
}
__device__ __forceinline__ float unpackV(u64 key) {
    u32 hu = (u32)(key >> 32);
    return (hu & 0x80000000u) ? __uint_as_float(hu & 0x7fffffffu)
                              : __uint_as_float(~hu);
}

// branchless merge of two sorted-desc lists, keep first LO into a[]
template<int LO, int LA, int LB, typename T>
__device__ __forceinline__ void mergeKeep(T a[LA], const T b[LB]) {
    T A[LA], B[LB], out[LO];
#pragma unroll
    for (int i = 0; i < LA; ++i) A[i] = a[i];
#pragma unroll
    for (int i = 0; i < LB; ++i) B[i] = b[i];
#pragma unroll
    for (int m = 0; m < LO; ++m) {
        bool ta = A[0] >= B[0];
        out[m] = ta ? A[0] : B[0];
#pragma unroll
        for (int i = 0; i < LA - 1; ++i) A[i] = ta ? A[i + 1] : A[i];
        A[LA - 1] = ta ? (T)0 : A[LA - 1];
#pragma unroll
        for (int i = 0; i < LB - 1; ++i) B[i] = ta ? B[i] : B[i + 1];
        B[LB - 1] = ta ? B[LB - 1] : (T)0;
    }
#pragma unroll
    for (int m = 0; m < LO; ++m) a[m] = out[m];
}

// ---------------------------------------------------------------------------
// Prep: repack x into MFMA-fragment order + row norms (raw and -0.5x for the
// MFMA C-operand fold).
// xbA[tile][khalf][lane][8 bf16]: lane = q*16+r holds x[tile*16+r][kh*32+q*8..+8).
// ---------------------------------------------------------------------------
__global__ __launch_bounds__(256) void prep(
    const float* __restrict__ x, __bf16* __restrict__ xbA,
    float* __restrict__ xxf, float* __restrict__ xxh, int N)
{
    int g = blockIdx.x * 256 + threadIdx.x;
    const int REPACK = NTILES * 2 * 64;          // 80000
    if (g < REPACK) {
        int tile = g >> 7;
        int rem  = g & 127;
        int kh   = rem >> 6;
        int lane = rem & 63;
        int q = lane >> 4, r = lane & 15;
        int row = tile * 16 + r;
        int k0  = kh * 32 + q * 8;
        const float4* p = (const float4*)(x + (size_t)row * D + k0);
        float4 v0 = p[0], v1 = p[1];
        bf16x8 o;
        o[0] = (__bf16)v0.x; o[1] = (__bf16)v0.y; o[2] = (__bf16)v0.z; o[3] = (__bf16)v0.w;
        o[4] = (__bf16)v1.x; o[5] = (__bf16)v1.y; o[6] = (__bf16)v1.z; o[7] = (__bf16)v1.w;
        ((bf16x8*)xbA)[g] = o;
        return;
    }
    int i = g - REPACK;
    if (i >= N) return;
    const float4* p = (const float4*)(x + (size_t)i * D);
    float s = 0.f;
#pragma unroll
    for (int t = 0; t < 16; ++t) {
        float4 v = p[t];
        s += v.x * v.x + v.y * v.y + v.z * v.z + v.w * v.w;
    }
    xxf[i] = s;
    xxh[i] = -0.5f * s;
}

// ---------------------------------------------------------------------------
// Round-11: ALL-COLUMN blocks — wsK round-trip and the rescore kernel
// eliminated. One block per 16-row tile (625 x 512 threads = 4.9 waves/SIMD,
// r9's proven occupancy). All 8 waves share the B fragments; wave w scans
// column-tile residue (7-w) mod 8 (~78 iters) with the r10 loop body:
// 1-deep prefetch, -0.5||xj||^2 folded into the MFMA C-operand, cheap key
// pack, med3 insert network, and ONE plain guarded zero-store per iter
// (block slice = 40000 f4; 78.1 slots/thread needed, 78-79 available,
// tail drain covers the edge; plain stores proven +17us over NT in r10).
// Then quad butterfly -> 4KB LDS (8 lists/row) -> wave 0 runs the verified
// r2 stage-2: 4 lanes/row merge to top-12, exact fp32 rescore (3 cands/
// lane), exact u64 top-5 -> ws5. No out access here -> no race with the
// zero stream; the tiny scatter kernel runs after.
// ---------------------------------------------------------------------------
__global__ __launch_bounds__(512) void topk_zero_mfma(
    const __bf16* __restrict__ xbA, const float* __restrict__ xxf,
    const float* __restrict__ xxh, const float* __restrict__ x, int N,
    float* __restrict__ outZ, long long totalF4, int f4PerB,
    u64* __restrict__ ws5)
{
    const int rb  = blockIdx.x;                  // rows rb*16 .. rb*16+15
    const int tid = threadIdx.x;
    const int lane = tid & 63;
    const int wave = tid >> 6;                   // 0..7
    const int l15  = lane & 15;
    const int q    = lane >> 4;                  // col quad

    // my zero slice [zi, ze) in float4 units
    long long zi = (long long)rb * f4PerB + tid;
    long long ze = (long long)(rb + 1) * f4PerB;
    if (ze > totalF4) ze = totalF4;
    const f32x4v zv = {0.f, 0.f, 0.f, 0.f};

    const bf16x8* fb = (const bf16x8*)xbA;       // fragment base, 128 per tile

    // B fragments: this block's 16-row tile
    const bf16x8 B0 = fb[rb * 128 + lane];
    const bf16x8 B1 = fb[rb * 128 + 64 + lane];

    const int t0 = 7 - wave;                     // wave0 -> residue 7 (78 iters):
                                                 // it also runs the stage-2 tail
    const bf16x8* ap = fb + (size_t)t0 * 128 + lane;
    const float* xhp = xxh + t0 * 16 + q * 4;
    u32 base16k = 0x3FFFu - (u32)(t0 * 16 + q * 4);      // 0x3FFF - cbase
    const int apBump = NW * 128;                 // 1024 fragments
    const int xcBump = NW * 16;                  // 128 floats

    u32 L[LK];
#pragma unroll
    for (int m = 0; m < LK; ++m) L[m] = 0u;      // 0 < any real packed key

    // 1-deep software pipeline; prefetch overruns <=8 tiles (16 KB) past
    // xbA and ~0.5 KB past xxh — workspace pads cover both.
    bf16x8 A0 = ap[0];
    bf16x8 A1 = ap[64];
    f32x4v xh = *(const f32x4v*)xhp;

    for (int t = t0; t < NTILES; t += NW) {
        ap += apBump; xhp += xcBump;
        const bf16x8 nA0 = ap[0];
        const bf16x8 nA1 = ap[64];
        const f32x4v nxh = *(const f32x4v*)xhp;

        // zero-stream slice: 1 guarded PLAIN store (512 f4 per block-iter),
        // issued before the insert burst so the drain overlaps the VALU work
        if (zi < ze)
            *(f32x4v*)(outZ + 4 * zi) = zv;
        zi += 512;

        f32x4v acc = xh;                          // C init = -0.5*||xj||^2
        acc = __builtin_amdgcn_mfma_f32_16x16x32_bf16(A0, B0, acc, 0, 0, 0);
        acc = __builtin_amdgcn_mfma_f32_16x16x32_bf16(A1, B1, acc, 0, 0, 0);

        // monotone key map (5 ops) + med3 insertion (8 ops) per candidate
#pragma unroll
        for (int v = 0; v < 4; ++v) {
            u32 u = __float_as_uint(acc[v]);
            u ^= ((u32)((int)u >> 31)) | 0x80000000u;
            u32 key = (u & 0xFFFFC000u) | (base16k - (u32)v);
            u32 n0 = max(L[0], key);
            u32 n1 = med3u(L[0], L[1], key);
            u32 n2 = med3u(L[1], L[2], key);
            u32 n3 = med3u(L[2], L[3], key);
            u32 n4 = med3u(L[3], L[4], key);
            u32 n5 = med3u(L[4], L[5], key);
            u32 n6 = med3u(L[5], L[6], key);
            u32 n7 = med3u(L[6], L[7], key);
            L[0]=n0; L[1]=n1; L[2]=n2; L[3]=n3; L[4]=n4; L[5]=n5; L[6]=n6; L[7]=n7;
        }
        base16k -= (u32)xcBump;
        A0 = nA0; A1 = nA1; xh = nxh;
    }

    // tail drain (covers the exact-fit boundary between slots and slice)
    while (zi < ze) {
        *(f32x4v*)(outZ + 4 * zi) = zv;
        zi += 512;
    }

    // butterfly merge across the 4 quads sharing a row -> per-wave top-8/row
#pragma unroll
    for (int mask = 16; mask <= 32; mask <<= 1) {
        u32 P[LK];
#pragma unroll
        for (int m = 0; m < LK; ++m) P[m] = (u32)__shfl_xor((int)L[m], mask);
        mergeKeep<LK, LK, LK, u32>(L, P);
    }

    __shared__ u32 lsd[NW][16][LK];              // 4 KB
    if (lane < 16) {
#pragma unroll
        for (int m = 0; m < LK; ++m) lsd[wave][lane][m] = L[m];
    }
    __syncthreads();
    if (wave != 0) return;

    // ---- stage 2 (wave 0, verified in r2): 4 lanes per row ----
    const int sub = lane & 3;
    const int rl  = lane >> 2;
    const int row = rb * 16 + rl;
    const bool vrow = (row < N);
    const int rr = vrow ? row : 0;

    u32 cur[GK];
#pragma unroll
    for (int m = 0; m < LK; ++m) cur[m] = lsd[2 * sub][rl][m];
#pragma unroll
    for (int m = LK; m < GK; ++m) cur[m] = 0u;
    {
        u32 b[LK];
#pragma unroll
        for (int m = 0; m < LK; ++m) b[m] = lsd[2 * sub + 1][rl][m];
        mergeKeep<GK, GK, LK, u32>(cur, b);
    }
#pragma unroll
    for (int mask = 1; mask <= 2; mask <<= 1) {
        u32 P[GK];
#pragma unroll
        for (int m = 0; m < GK; ++m) P[m] = (u32)__shfl_xor((int)cur[m], mask);
        mergeKeep<GK, GK, GK, u32>(cur, P);
    }

    // exact fp32 rescore of my 3 candidates
    const float nxi = xxf[rr];
    int   cj[3]; bool cval[3];
    float d[3] = {0.f, 0.f, 0.f};
    const f32x4v* pj[3];
#pragma unroll
    for (int c = 0; c < 3; ++c) {
        int j = idx32(cur[sub * 3 + c]);
        cval[c] = (j < N) && (cur[sub * 3 + c] != 0u);
        cj[c] = cval[c] ? j : 0;
        pj[c] = (const f32x4v*)(x + (size_t)cj[c] * D);
    }
    const f32x4v* xip = (const f32x4v*)(x + (size_t)rr * D);
#pragma unroll
    for (int t = 0; t < 16; ++t) {
        const f32x4v xv = xip[t];
#pragma unroll
        for (int c = 0; c < 3; ++c) {
            const f32x4v pv = pj[c][t];
            d[c] = fmaf(xv[0], pv[0], d[c]);
            d[c] = fmaf(xv[1], pv[1], d[c]);
            d[c] = fmaf(xv[2], pv[2], d[c]);
            d[c] = fmaf(xv[3], pv[3], d[c]);
        }
    }
    u64 F[K];
#pragma unroll
    for (int c = 0; c < 3; ++c) {
        float val = 2.f * d[c] - nxi - xxf[cj[c]];
        F[c] = cval[c] ? packKV(val, cj[c]) : 0ull;
    }
    F[3] = 0ull; F[4] = 0ull;
    // sort first 3 desc
    { u64 a0=F[0],a1=F[1],a2=F[2];
      if (a0 < a1) { u64 t0s=a0; a0=a1; a1=t0s; }
      if (a1 < a2) { u64 t0s=a1; a1=a2; a2=t0s; }
      if (a0 < a1) { u64 t0s=a0; a0=a1; a1=t0s; }
      F[0]=a0; F[1]=a1; F[2]=a2; }
#pragma unroll
    for (int mask = 1; mask <= 2; mask <<= 1) {
        u64 P[K];
#pragma unroll
        for (int m = 0; m < K; ++m) P[m] = __shfl_xor(F[m], mask);
        mergeKeep<K, K, K, u64>(F, P);
    }

    if (sub == 0 && vrow) {
#pragma unroll
        for (int m = 0; m < K; ++m) ws5[(size_t)row * K + m] = F[m];
    }
}

// ---------------------------------------------------------------------------
// Scatter: one thread per row; symmetric atomic adds (out fully zeroed by
// topk_zero_mfma, which precedes on the stream).
// ---------------------------------------------------------------------------
__global__ __launch_bounds__(256) void scatter(
    const u64* __restrict__ ws5, float* __restrict__ out, int N)
{
    int row = blockIdx.x * 256 + threadIdx.x;
    if (row >= N) return;
#pragma unroll
    for (int m = 0; m < K; ++m) {
        u64 f = ws5[(size_t)row * K + m];
        int j = (int)(~(u32)f);
        if ((unsigned)j < (unsigned)N && j != row) {
            float v = unpackV(f);
            atomicAdd(out + (size_t)row * N + j, v);
            atomicAdd(out + (size_t)j * N + row, v);
        }
    }
}

// ---------------------------------------------------------------------------
extern "C" void kernel_launch(void* const* d_in, const int* in_sizes, int n_in,
                              void* d_out, int out_size, void* d_ws, size_t ws_size,
                              hipStream_t stream) {
    const float* x = (const float*)d_in[0];
    const int N = in_sizes[0] / D;          // 10000
    float* out = (float*)d_out;

    // Workspace layout (fixed offsets; pads cover the 1-deep prefetch
    // overrun: <=8 tiles = 16 KB past xbA, ~0.5 KB past xxh):
    //   xbA @ 0x000000: 625*128*16B = 1.28 MB (+pad)  -> ends < 0x150000
    //   xxf @ 0x150000: 40 KB raw norms
    //   xxh @ 0x160000: 40 KB (-0.5*norm) (+24 KB pad)
    //   ws5 @ 0x170000: N*K u64 = 400 KB
    const size_t oXB = 0;
    const size_t oXX = 0x150000;
    const size_t oXH = 0x160000;
    const size_t oW5 = 0x170000;
    __bf16* xbA = (__bf16*)((char*)d_ws + oXB);
    float*  xxf = (float*)((char*)d_ws + oXX);
    float*  xxh = (float*)((char*)d_ws + oXH);
    u64*    ws5 = (u64*)((char*)d_ws + oW5);

    prep<<<PREPBLK, 256, 0, stream>>>(x, xbA, xxf, xxh, N);

    long long totalF4 = (long long)out_size / 16;        // 25e6 float4
    int f4PerB = (int)((totalF4 + NTILES - 1) / NTILES); // 40000
    topk_zero_mfma<<<NTILES, 512, 0, stream>>>(
        xbA, xxf, xxh, x, N, out, totalF4, f4PerB, ws5);

    scatter<<<(N + 255) / 256, 256, 0, stream>>>(ws5, out, N);
}

// Round 12
// 403.077 us; speedup vs baseline: 1.0983x; 1.0983x over previous
//
#include <hip/hip_runtime.h>

#define D 64
#define K 5
#define LK 8                  // per-lane / per-split candidate list length
#define GK 12                 // global candidates rescored per row
#define NSPLIT 16
#define NTILES 625            // 10000 / 16 exactly
#define RWAVE 2               // row-tiles (16 rows each) per wave -> 32 rows/wave
#define RBLK 79               // ceil(10000/128) row-blocks (128 rows per block)
#define NCOMP (RBLK * NSPLIT) // 1264 compute blocks (== the whole grid)
typedef unsigned int u32;
typedef unsigned long long u64;
typedef __bf16 bf16x8 __attribute__((ext_vector_type(8)));
typedef float  f32x4v __attribute__((ext_vector_type(4)));

// v_med3_u32 (GCN3+; no HIP builtin)
__device__ __forceinline__ u32 med3u(u32 a, u32 b, u32 c) {
    u32 r;
    asm("v_med3_u32 %0, %1, %2, %3" : "=v"(r) : "v"(a), "v"(b), "v"(c));
    return r;
}

// ---- u32 key: [31:14] = top bits of FULL monotone fp32 map, [13:0] = 0x3FFF-idx
// (== (~idx)&0x3FFF for idx<16384). bigger key == (bigger value, then lower idx).
__device__ __forceinline__ int idx32(u32 key) { return (int)((~key) & 0x3FFFu); }

// exact final key (value, then lower idx)
__device__ __forceinline__ u64 packKV(float v, int idx) {
    u32 u = __float_as_uint(v);
    u ^= ((u32)((int)u >> 31)) | 0x80000000u;
    return ((u64)u << 32) | (u32)(~idx);
}
__device__ __forceinline__ float unpackV(u64 key) {
    u32 hu = (u32)(key >> 32);
    return (hu & 0x80000000u) ? __uint_as_float(hu & 0x7fffffffu)
                              : __uint_as_float(~hu);
}

// branchless merge of two sorted-desc lists, keep first LO into a[]
template<int LO, int LA, int LB, typename T>
__device__ __forceinline__ void mergeKeep(T a[LA], const T b[LB]) {
    T A[LA], B[LB], out[LO];
#pragma unroll
    for (int i = 0; i < LA; ++i) A[i] = a[i];
#pragma unroll
    for (int i = 0; i < LB; ++i) B[i] = b[i];
#pragma unroll
    for (int m = 0; m < LO; ++m) {
        bool ta = A[0] >= B[0];
        out[m] = ta ? A[0] : B[0];
#pragma unroll
        for (int i = 0; i < LA - 1; ++i) A[i] = ta ? A[i + 1] : A[i];
        A[LA - 1] = ta ? (T)0 : A[LA - 1];
#pragma unroll
        for (int i = 0; i < LB - 1; ++i) B[i] = ta ? B[i] : B[i + 1];
        B[LB - 1] = ta ? B[LB - 1] : (T)0;
    }
#pragma unroll
    for (int m = 0; m < LO; ++m) a[m] = out[m];
}

// ---------------------------------------------------------------------------
// Prep: repack x into MFMA-fragment order + row norms (raw and -0.5x for the
// MFMA C-operand fold).
// xbA[tile][khalf][lane][8 bf16]: lane = q*16+r holds x[tile*16+r][kh*32+q*8..+8).
// ---------------------------------------------------------------------------
__global__ __launch_bounds__(256) void prep(
    const float* __restrict__ x, __bf16* __restrict__ xbA,
    float* __restrict__ xxf, float* __restrict__ xxh, int N)
{
    int g = blockIdx.x * 256 + threadIdx.x;
    const int REPACK = NTILES * 2 * 64;          // 80000
    if (g < REPACK) {
        int tile = g >> 7;
        int rem  = g & 127;
        int kh   = rem >> 6;
        int lane = rem & 63;
        int q = lane >> 4, r = lane & 15;
        int row = tile * 16 + r;
        int k0  = kh * 32 + q * 8;
        const float4* p = (const float4*)(x + (size_t)row * D + k0);
        float4 v0 = p[0], v1 = p[1];
        bf16x8 o;
        o[0] = (__bf16)v0.x; o[1] = (__bf16)v0.y; o[2] = (__bf16)v0.z; o[3] = (__bf16)v0.w;
        o[4] = (__bf16)v1.x; o[5] = (__bf16)v1.y; o[6] = (__bf16)v1.z; o[7] = (__bf16)v1.w;
        ((bf16x8*)xbA)[g] = o;
        return;
    }
    int i = g - REPACK;
    if (i >= N) return;
    const float4* p = (const float4*)(x + (size_t)i * D);
    float s = 0.f;
#pragma unroll
    for (int t = 0; t < 16; ++t) {
        float4 v = p[t];
        s += v.x * v.x + v.y * v.y + v.z * v.z + v.w * v.w;
    }
    xxf[i] = s;
    xxh[i] = -0.5f * s;
}

// ---------------------------------------------------------------------------
// Fused scan + zero (r10 champion, byte-identical): plain stores issued
// before the insert burst; 1264 blocks (~4.9 waves/SIMD), RWAVE=2, 1-deep
// prefetch, acc-init fold, cheap key pack, med3 insert network, tail drain.
// ---------------------------------------------------------------------------
__global__ __launch_bounds__(256) void topk_zero_mfma(
    const __bf16* __restrict__ xbA, const float* __restrict__ xxh, int N,
    u32* __restrict__ wsK, float* __restrict__ outZ, long long totalF4,
    int f4PerB)
{
    const int bx  = blockIdx.x;
    const int tid = threadIdx.x;

    const int split = bx / RBLK;                 // 0..15
    const int rb    = bx - split * RBLK;         // 0..78

    const int lane = tid & 63;
    const int wave = tid >> 6;
    const int l15  = lane & 15;
    const int q    = lane >> 4;                  // col quad
    const int r0   = rb * 128 + wave * 32;       // first of this wave's 32 rows

    // my zero slice [zi, ze) in float4 units
    long long zi = (long long)bx * f4PerB + tid;
    long long ze = (long long)(bx + 1) * f4PerB;
    if (ze > totalF4) ze = totalF4;
    const f32x4v zv = {0.f, 0.f, 0.f, 0.f};

    const bf16x8* fb = (const bf16x8*)xbA;       // fragment base, 128 per tile

    // B fragments: 2 row-tiles (clamped at the table end for tail waves)
    bf16x8 Bf[RWAVE][2];
#pragma unroll
    for (int l = 0; l < RWAVE; ++l) {
        int bt = (r0 >> 4) + l; if (bt > NTILES - 1) bt = NTILES - 1;
        Bf[l][0] = fb[bt * 128 + lane];
        Bf[l][1] = fb[bt * 128 + 64 + lane];
    }

    // pointer-bumped loop state
    const bf16x8* ap = fb + (size_t)split * 128 + lane;
    const float* xhp = xxh + split * 16 + q * 4;
    u32 base16k = 0x3FFFu - (u32)(split * 16 + q * 4);   // 0x3FFF - cbase
    const int apBump = NSPLIT * 128;             // 2048 fragments
    const int xcBump = NSPLIT * 16;              // 256 floats

    u32 L[RWAVE][LK];
#pragma unroll
    for (int l = 0; l < RWAVE; ++l)
#pragma unroll
        for (int m = 0; m < LK; ++m) L[l][m] = 0u;   // 0 < any real packed key

    // 1-deep software pipeline; prefetch overruns <=16 tiles (32 KB) past
    // xbA and ~1 KB past xxh — workspace pads cover both.
    bf16x8 A0 = ap[0];
    bf16x8 A1 = ap[64];
    f32x4v xh = *(const f32x4v*)xhp;

    for (int t = split; t < NTILES; t += NSPLIT) {
        ap += apBump; xhp += xcBump;
        const bf16x8 nA0 = ap[0];
        const bf16x8 nA1 = ap[64];
        const f32x4v nxh = *(const f32x4v*)xhp;

        // zero-stream slice: 2 guarded PLAIN stores issued before the insert
        // burst (write drain overlaps the VALU work below)
#pragma unroll
        for (int j = 0; j < 2; ++j) {
            if (zi < ze)
                *(f32x4v*)(outZ + 4 * zi) = zv;
            zi += 256;
        }

#pragma unroll
        for (int l = 0; l < RWAVE; ++l) {
            f32x4v acc = xh;                      // C init = -0.5*||xj||^2
            acc = __builtin_amdgcn_mfma_f32_16x16x32_bf16(A0, Bf[l][0], acc, 0, 0, 0);
            acc = __builtin_amdgcn_mfma_f32_16x16x32_bf16(A1, Bf[l][1], acc, 0, 0, 0);

            // monotone key map (5 ops) + med3 insertion (8 ops) per candidate
#pragma unroll
            for (int v = 0; v < 4; ++v) {
                u32 u = __float_as_uint(acc[v]);
                u ^= ((u32)((int)u >> 31)) | 0x80000000u;
                u32 key = (u & 0xFFFFC000u) | (base16k - (u32)v);
                u32 n0 = max(L[l][0], key);
                u32 n1 = med3u(L[l][0], L[l][1], key);
                u32 n2 = med3u(L[l][1], L[l][2], key);
                u32 n3 = med3u(L[l][2], L[l][3], key);
                u32 n4 = med3u(L[l][3], L[l][4], key);
                u32 n5 = med3u(L[l][4], L[l][5], key);
                u32 n6 = med3u(L[l][5], L[l][6], key);
                u32 n7 = med3u(L[l][6], L[l][7], key);
                L[l][0]=n0; L[l][1]=n1; L[l][2]=n2; L[l][3]=n3;
                L[l][4]=n4; L[l][5]=n5; L[l][6]=n6; L[l][7]=n7;
            }
        }
        base16k -= (u32)xcBump;
        A0 = nA0; A1 = nA1; xh = nxh;
    }

    // tail drain (covers the exact-fit boundary between slots and slice)
    while (zi < ze) {
        *(f32x4v*)(outZ + 4 * zi) = zv;
        zi += 256;
    }

    // per row-tile: butterfly merge across the 4 quads sharing a row, then
    // lane<16 writes that row's split-list to wsK
#pragma unroll
    for (int l = 0; l < RWAVE; ++l) {
#pragma unroll
        for (int mask = 16; mask <= 32; mask <<= 1) {
            u32 P[LK];
#pragma unroll
            for (int m = 0; m < LK; ++m) P[m] = (u32)__shfl_xor((int)L[l][m], mask);
            mergeKeep<LK, LK, LK, u32>(L[l], P);
        }
        if (lane < 16) {
            int row = r0 + l * 16 + l15;
            if (row < N) {
                u32* dst = wsK + ((size_t)row * NSPLIT + split) * LK;
#pragma unroll
                for (int m = 0; m < LK; ++m) dst[m] = L[l][m];
            }
        }
    }
}

// ---------------------------------------------------------------------------
// Round-12 rescore: 16 LANES PER ROW (was 4). The old shape had only 625
// waves machine-wide (0.6/SIMD) running long serial merge chains + 48
// serial 16B gathers per lane — occupancy-starved. Now: each lane owns ONE
// of the row's 16 split-lists (32B coalesced; a 16-lane group reads the
// row's 512B contiguously), 4 shfl_xor butterflies (1,2,4,8) produce the
// global top-12 in every lane (merge-keep-top-k is associative => identical
// result & tie-breaks as the serial version). Lane c<12 rescores candidate
// c exactly; final exact u64 top-5 via 4-step butterfly of 1->5 lists.
// 2500 waves, 4x shorter chains, same work, same atomics.
// ---------------------------------------------------------------------------
__global__ __launch_bounds__(256) void rescore_scatter(
    const u32* __restrict__ wsK, const float* __restrict__ x, const float* __restrict__ xxf,
    float* __restrict__ out, int N)
{
    const int lane  = threadIdx.x & 63;
    const int wave  = threadIdx.x >> 6;
    const int sub   = lane & 15;                 // split / candidate slot
    const int row   = blockIdx.x * 16 + wave * 4 + (lane >> 4);
    const bool vrow = (row < N);
    const int rr = vrow ? row : 0;

    // my split-list -> 12-slot frame; butterflies to global top-12
    u32 cur[GK];
    {
        const u32* Lp = wsK + ((size_t)rr * NSPLIT + sub) * LK;
#pragma unroll
        for (int m = 0; m < LK; ++m) cur[m] = Lp[m];
#pragma unroll
        for (int m = LK; m < GK; ++m) cur[m] = 0u;
    }
#pragma unroll
    for (int mask = 1; mask <= 8; mask <<= 1) {
        u32 P[GK];
#pragma unroll
        for (int m = 0; m < GK; ++m) P[m] = (u32)__shfl_xor((int)cur[m], mask);
        mergeKeep<GK, GK, GK, u32>(cur, P);
    }

    // exact fp32 rescore of candidate sub (lanes 12..15 idle-valid)
    u64 f0 = 0ull;
    if (sub < GK) {
        u32 key = cur[sub];
        int j = idx32(key);
        bool cv = (j < N) && (key != 0u);
        int cj = cv ? j : 0;
        const f32x4v* pj = (const f32x4v*)(x + (size_t)cj * D);
        const f32x4v* xip = (const f32x4v*)(x + (size_t)rr * D);
        float d = 0.f;
#pragma unroll
        for (int t = 0; t < 16; ++t) {
            const f32x4v xv = xip[t];
            const f32x4v pv = pj[t];
            d = fmaf(xv[0], pv[0], d);
            d = fmaf(xv[1], pv[1], d);
            d = fmaf(xv[2], pv[2], d);
            d = fmaf(xv[3], pv[3], d);
        }
        float val = 2.f * d - xxf[rr] - xxf[cj];
        f0 = cv ? packKV(val, cj) : 0ull;
    }

    // exact u64 top-5 across the 16-lane group
    u64 F[K];
    F[0] = f0; F[1] = 0ull; F[2] = 0ull; F[3] = 0ull; F[4] = 0ull;
#pragma unroll
    for (int mask = 1; mask <= 8; mask <<= 1) {
        u64 P[K];
#pragma unroll
        for (int m = 0; m < K; ++m) P[m] = __shfl_xor(F[m], mask);
        mergeKeep<K, K, K, u64>(F, P);
    }

    if (sub == 0 && vrow) {
#pragma unroll
        for (int m = 0; m < K; ++m) {
            int j = (int)(~(u32)F[m]);
            if ((unsigned)j < (unsigned)N && j != row) {
                float v = unpackV(F[m]);
                atomicAdd(out + (size_t)row * N + j, v);
                atomicAdd(out + (size_t)j * N + row, v);
            }
        }
    }
}

// ---------------------------------------------------------------------------
extern "C" void kernel_launch(void* const* d_in, const int* in_sizes, int n_in,
                              void* d_out, int out_size, void* d_ws, size_t ws_size,
                              hipStream_t stream) {
    const float* x = (const float*)d_in[0];
    const int N = in_sizes[0] / D;          // 10000
    float* out = (float*)d_out;

    // Workspace layout (fixed offsets; pads cover the 1-deep prefetch
    // overrun: <=16 tiles = 32 KB past xbA, ~1 KB past xxh):
    //   xbA @ 0x000000: 625*128*16B = 1.28 MB (+pad)  -> ends < 0x150000
    //   xxf @ 0x150000: 40 KB raw norms
    //   xxh @ 0x160000: 40 KB (-0.5*norm) (+24 KB pad)
    //   wsK @ 0x170000: N*NSPLIT*LK u32 = 5.12 MB
    const size_t oXB = 0;
    const size_t oXX = 0x150000;
    const size_t oXH = 0x160000;
    const size_t oWK = 0x170000;
    __bf16* xbA = (__bf16*)((char*)d_ws + oXB);
    float*  xxf = (float*)((char*)d_ws + oXX);
    float*  xxh = (float*)((char*)d_ws + oXH);
    u32*    wsK = (u32*)((char*)d_ws + oWK);

    const int prepThreads = NTILES * 2 * 64 + N;         // 90000
    prep<<<(prepThreads + 255) / 256, 256, 0, stream>>>(x, xbA, xxf, xxh, N);

    long long totalF4 = (long long)out_size / 16;        // 25e6 float4
    int f4PerB = (int)((totalF4 + NCOMP - 1) / NCOMP);   // 19779
    topk_zero_mfma<<<NCOMP, 256, 0, stream>>>(
        xbA, xxh, N, wsK, out, totalF4, f4PerB);

    rescore_scatter<<<NTILES, 256, 0, stream>>>(wsK, x, xxf, out, N);
}

// Round 13
// 398.363 us; speedup vs baseline: 1.1113x; 1.0118x over previous
//
#include <hip/hip_runtime.h>

#define D 64
#define K 5
#define LK 8                  // per-lane / per-split candidate list length
#define GK 12                 // global candidates rescored per row
#define NSPLIT 16
#define NTILES 625            // 10000 / 16 exactly
#define RWAVE 2               // row-tiles (16 rows each) per wave -> 32 rows/wave
#define RBLK 79               // ceil(10000/128) row-blocks (128 rows per block)
#define NCOMP (RBLK * NSPLIT) // 1264 compute blocks (== the whole grid)
typedef unsigned int u32;
typedef unsigned long long u64;
typedef __bf16 bf16x8 __attribute__((ext_vector_type(8)));
typedef float  f32x4v __attribute__((ext_vector_type(4)));

// v_med3_u32 (GCN3+; no HIP builtin)
__device__ __forceinline__ u32 med3u(u32 a, u32 b, u32 c) {
    u32 r;
    asm("v_med3_u32 %0, %1, %2, %3" : "=v"(r) : "v"(a), "v"(b), "v"(c));
    return r;
}

// ---- u32 key: [31:14] = top bits of FULL monotone fp32 map, [13:0] = 0x3FFF-idx
// (== (~idx)&0x3FFF for idx<16384). bigger key == (bigger value, then lower idx).
__device__ __forceinline__ int idx32(u32 key) { return (int)((~key) & 0x3FFFu); }

// exact final key (value, then lower idx)
__device__ __forceinline__ u64 packKV(float v, int idx) {
    u32 u = __float_as_uint(v);
    u ^= ((u32)((int)u >> 31)) | 0x80000000u;
    return ((u64)u << 32) | (u32)(~idx);
}
__device__ __forceinline__ float unpackV(u64 key) {
    u32 hu = (u32)(key >> 32);
    return (hu & 0x80000000u) ? __uint_as_float(hu & 0x7fffffffu)
                              : __uint_as_float(~hu);
}

// branchless merge of two sorted-desc lists, keep first LO into a[]
template<int LO, int LA, int LB, typename T>
__device__ __forceinline__ void mergeKeep(T a[LA], const T b[LB]) {
    T A[LA], B[LB], out[LO];
#pragma unroll
    for (int i = 0; i < LA; ++i) A[i] = a[i];
#pragma unroll
    for (int i = 0; i < LB; ++i) B[i] = b[i];
#pragma unroll
    for (int m = 0; m < LO; ++m) {
        bool ta = A[0] >= B[0];
        out[m] = ta ? A[0] : B[0];
#pragma unroll
        for (int i = 0; i < LA - 1; ++i) A[i] = ta ? A[i + 1] : A[i];
        A[LA - 1] = ta ? (T)0 : A[LA - 1];
#pragma unroll
        for (int i = 0; i < LB - 1; ++i) B[i] = ta ? B[i] : B[i + 1];
        B[LB - 1] = ta ? B[LB - 1] : (T)0;
    }
#pragma unroll
    for (int m = 0; m < LO; ++m) a[m] = out[m];
}

// ---------------------------------------------------------------------------
// Prep: repack x into MFMA-fragment order + row norms (raw and -0.5x for the
// MFMA C-operand fold).
// xbA[tile][khalf][lane][8 bf16]: lane = q*16+r holds x[tile*16+r][kh*32+q*8..+8).
// ---------------------------------------------------------------------------
__global__ __launch_bounds__(256) void prep(
    const float* __restrict__ x, __bf16* __restrict__ xbA,
    float* __restrict__ xxf, float* __restrict__ xxh, int N)
{
    int g = blockIdx.x * 256 + threadIdx.x;
    const int REPACK = NTILES * 2 * 64;          // 80000
    if (g < REPACK) {
        int tile = g >> 7;
        int rem  = g & 127;
        int kh   = rem >> 6;
        int lane = rem & 63;
        int q = lane >> 4, r = lane & 15;
        int row = tile * 16 + r;
        int k0  = kh * 32 + q * 8;
        const float4* p = (const float4*)(x + (size_t)row * D + k0);
        float4 v0 = p[0], v1 = p[1];
        bf16x8 o;
        o[0] = (__bf16)v0.x; o[1] = (__bf16)v0.y; o[2] = (__bf16)v0.z; o[3] = (__bf16)v0.w;
        o[4] = (__bf16)v1.x; o[5] = (__bf16)v1.y; o[6] = (__bf16)v1.z; o[7] = (__bf16)v1.w;
        ((bf16x8*)xbA)[g] = o;
        return;
    }
    int i = g - REPACK;
    if (i >= N) return;
    const float4* p = (const float4*)(x + (size_t)i * D);
    float s = 0.f;
#pragma unroll
    for (int t = 0; t < 16; ++t) {
        float4 v = p[t];
        s += v.x * v.x + v.y * v.y + v.z * v.z + v.w * v.w;
    }
    xxf[i] = s;
    xxh[i] = -0.5f * s;
}

// ---------------------------------------------------------------------------
// Fused scan + zero (session champion, r10): plain stores issued before the
// insert burst (L2 acts as elastic buffer between wave-side issue and HBM
// drain — proven +17us over NT); 1264 blocks (~4.9 waves/SIMD, proven +6 over
// 2.5), RWAVE=2 (proven +15 over RWAVE=... the iteration-fattening sweet
// spot), 1-deep prefetch (2-deep proven null), -0.5||xj||^2 folded into the
// MFMA C-operand, cheap key pack (base16k counter), med3 insert network,
// tail drain for the slot/slice boundary.
// ---------------------------------------------------------------------------
__global__ __launch_bounds__(256) void topk_zero_mfma(
    const __bf16* __restrict__ xbA, const float* __restrict__ xxh, int N,
    u32* __restrict__ wsK, float* __restrict__ outZ, long long totalF4,
    int f4PerB)
{
    const int bx  = blockIdx.x;
    const int tid = threadIdx.x;

    const int split = bx / RBLK;                 // 0..15
    const int rb    = bx - split * RBLK;         // 0..78

    const int lane = tid & 63;
    const int wave = tid >> 6;
    const int l15  = lane & 15;
    const int q    = lane >> 4;                  // col quad
    const int r0   = rb * 128 + wave * 32;       // first of this wave's 32 rows

    // my zero slice [zi, ze) in float4 units
    long long zi = (long long)bx * f4PerB + tid;
    long long ze = (long long)(bx + 1) * f4PerB;
    if (ze > totalF4) ze = totalF4;
    const f32x4v zv = {0.f, 0.f, 0.f, 0.f};

    const bf16x8* fb = (const bf16x8*)xbA;       // fragment base, 128 per tile

    // B fragments: 2 row-tiles (clamped at the table end for tail waves)
    bf16x8 Bf[RWAVE][2];
#pragma unroll
    for (int l = 0; l < RWAVE; ++l) {
        int bt = (r0 >> 4) + l; if (bt > NTILES - 1) bt = NTILES - 1;
        Bf[l][0] = fb[bt * 128 + lane];
        Bf[l][1] = fb[bt * 128 + 64 + lane];
    }

    // pointer-bumped loop state
    const bf16x8* ap = fb + (size_t)split * 128 + lane;
    const float* xhp = xxh + split * 16 + q * 4;
    u32 base16k = 0x3FFFu - (u32)(split * 16 + q * 4);   // 0x3FFF - cbase
    const int apBump = NSPLIT * 128;             // 2048 fragments
    const int xcBump = NSPLIT * 16;              // 256 floats

    u32 L[RWAVE][LK];
#pragma unroll
    for (int l = 0; l < RWAVE; ++l)
#pragma unroll
        for (int m = 0; m < LK; ++m) L[l][m] = 0u;   // 0 < any real packed key

    // 1-deep software pipeline; prefetch overruns <=16 tiles (32 KB) past
    // xbA and ~1 KB past xxh — workspace pads cover both.
    bf16x8 A0 = ap[0];
    bf16x8 A1 = ap[64];
    f32x4v xh = *(const f32x4v*)xhp;

    for (int t = split; t < NTILES; t += NSPLIT) {
        ap += apBump; xhp += xcBump;
        const bf16x8 nA0 = ap[0];
        const bf16x8 nA1 = ap[64];
        const f32x4v nxh = *(const f32x4v*)xhp;

        // zero-stream slice: 2 guarded PLAIN stores issued before the insert
        // burst (write drain overlaps the VALU work below)
#pragma unroll
        for (int j = 0; j < 2; ++j) {
            if (zi < ze)
                *(f32x4v*)(outZ + 4 * zi) = zv;
            zi += 256;
        }

#pragma unroll
        for (int l = 0; l < RWAVE; ++l) {
            f32x4v acc = xh;                      // C init = -0.5*||xj||^2
            acc = __builtin_amdgcn_mfma_f32_16x16x32_bf16(A0, Bf[l][0], acc, 0, 0, 0);
            acc = __builtin_amdgcn_mfma_f32_16x16x32_bf16(A1, Bf[l][1], acc, 0, 0, 0);

            // monotone key map (5 ops) + med3 insertion (8 ops) per candidate
#pragma unroll
            for (int v = 0; v < 4; ++v) {
                u32 u = __float_as_uint(acc[v]);
                u ^= ((u32)((int)u >> 31)) | 0x80000000u;
                u32 key = (u & 0xFFFFC000u) | (base16k - (u32)v);
                u32 n0 = max(L[l][0], key);
                u32 n1 = med3u(L[l][0], L[l][1], key);
                u32 n2 = med3u(L[l][1], L[l][2], key);
                u32 n3 = med3u(L[l][2], L[l][3], key);
                u32 n4 = med3u(L[l][3], L[l][4], key);
                u32 n5 = med3u(L[l][4], L[l][5], key);
                u32 n6 = med3u(L[l][5], L[l][6], key);
                u32 n7 = med3u(L[l][6], L[l][7], key);
                L[l][0]=n0; L[l][1]=n1; L[l][2]=n2; L[l][3]=n3;
                L[l][4]=n4; L[l][5]=n5; L[l][6]=n6; L[l][7]=n7;
            }
        }
        base16k -= (u32)xcBump;
        A0 = nA0; A1 = nA1; xh = nxh;
    }

    // tail drain (covers the exact-fit boundary between slots and slice)
    while (zi < ze) {
        *(f32x4v*)(outZ + 4 * zi) = zv;
        zi += 256;
    }

    // per row-tile: butterfly merge across the 4 quads sharing a row, then
    // lane<16 writes that row's split-list to wsK
#pragma unroll
    for (int l = 0; l < RWAVE; ++l) {
#pragma unroll
        for (int mask = 16; mask <= 32; mask <<= 1) {
            u32 P[LK];
#pragma unroll
            for (int m = 0; m < LK; ++m) P[m] = (u32)__shfl_xor((int)L[l][m], mask);
            mergeKeep<LK, LK, LK, u32>(L[l], P);
        }
        if (lane < 16) {
            int row = r0 + l * 16 + l15;
            if (row < N) {
                u32* dst = wsK + ((size_t)row * NSPLIT + split) * LK;
#pragma unroll
                for (int m = 0; m < LK; ++m) dst[m] = L[l][m];
            }
        }
    }
}

// ---------------------------------------------------------------------------
// 4 lanes per row (champion r10 version — the 16-lane widening measured
// neutral/noise, confirming this leg is off the critical path). Each lane
// merges 4 split-lists (u32); 2 shfl_xor butterflies give the global
// bf16-top-12. Each lane rescores 3 candidates in exact fp32; final top-5
// via exact packed-u64 butterfly (== reference tie-break). Lane 0 of each
// row does the symmetric atomic scatter.
// ---------------------------------------------------------------------------
__global__ __launch_bounds__(64) void rescore_scatter(
    const u32* __restrict__ wsK, const float* __restrict__ x, const float* __restrict__ xxf,
    float* __restrict__ out, int N)
{
    const int lane = threadIdx.x & 63;
    const int sub  = lane & 3;
    const int row  = blockIdx.x * 16 + (lane >> 2);
    const bool vrow = (row < N);
    const int rr = vrow ? row : 0;

    // merge my 4 lists, then butterfly to global top-12
    u32 cur[GK];
    {
        const u32* Lp = wsK + ((size_t)rr * NSPLIT + 4 * sub) * LK;
#pragma unroll
        for (int m = 0; m < LK; ++m) cur[m] = Lp[m];
#pragma unroll
        for (int m = LK; m < GK; ++m) cur[m] = 0u;
#pragma unroll
        for (int l = 1; l < 4; ++l) {
            u32 b[LK];
#pragma unroll
            for (int m = 0; m < LK; ++m) b[m] = Lp[l * LK + m];
            mergeKeep<GK, GK, LK, u32>(cur, b);
        }
    }
#pragma unroll
    for (int mask = 1; mask <= 2; mask <<= 1) {
        u32 P[GK];
#pragma unroll
        for (int m = 0; m < GK; ++m) P[m] = (u32)__shfl_xor((int)cur[m], mask);
        mergeKeep<GK, GK, GK, u32>(cur, P);
    }

    // exact fp32 rescore of my 3 candidates
    const float nxi = xxf[rr];
    int   cj[3]; bool cval[3];
    float d[3] = {0.f, 0.f, 0.f};
    const f32x4v* pj[3];
#pragma unroll
    for (int c = 0; c < 3; ++c) {
        int j = idx32(cur[sub * 3 + c]);
        cval[c] = (j < N) && (cur[sub * 3 + c] != 0u);
        cj[c] = cval[c] ? j : 0;
        pj[c] = (const f32x4v*)(x + (size_t)cj[c] * D);
    }
    const f32x4v* xip = (const f32x4v*)(x + (size_t)rr * D);
#pragma unroll
    for (int t = 0; t < 16; ++t) {
        const f32x4v xv = xip[t];
#pragma unroll
        for (int c = 0; c < 3; ++c) {
            const f32x4v pv = pj[c][t];
            d[c] = fmaf(xv[0], pv[0], d[c]);
            d[c] = fmaf(xv[1], pv[1], d[c]);
            d[c] = fmaf(xv[2], pv[2], d[c]);
            d[c] = fmaf(xv[3], pv[3], d[c]);
        }
    }
    u64 F[K];
#pragma unroll
    for (int c = 0; c < 3; ++c) {
        float val = 2.f * d[c] - nxi - xxf[cj[c]];
        F[c] = cval[c] ? packKV(val, cj[c]) : 0ull;
    }
    F[3] = 0ull; F[4] = 0ull;
    // sort first 3 desc
    { u64 a0=F[0],a1=F[1],a2=F[2];
      if (a0 < a1) { u64 t0=a0; a0=a1; a1=t0; }
      if (a1 < a2) { u64 t0=a1; a1=a2; a2=t0; }
      if (a0 < a1) { u64 t0=a0; a0=a1; a1=t0; }
      F[0]=a0; F[1]=a1; F[2]=a2; }
#pragma unroll
    for (int mask = 1; mask <= 2; mask <<= 1) {
        u64 P[K];
#pragma unroll
        for (int m = 0; m < K; ++m) P[m] = __shfl_xor(F[m], mask);
        mergeKeep<K, K, K, u64>(F, P);
    }

    if (sub == 0 && vrow) {
#pragma unroll
        for (int m = 0; m < K; ++m) {
            int j = (int)(~(u32)F[m]);
            if ((unsigned)j < (unsigned)N && j != row) {
                float v = unpackV(F[m]);
                atomicAdd(out + (size_t)row * N + j, v);
                atomicAdd(out + (size_t)j * N + row, v);
            }
        }
    }
}

// ---------------------------------------------------------------------------
extern "C" void kernel_launch(void* const* d_in, const int* in_sizes, int n_in,
                              void* d_out, int out_size, void* d_ws, size_t ws_size,
                              hipStream_t stream) {
    const float* x = (const float*)d_in[0];
    const int N = in_sizes[0] / D;          // 10000
    float* out = (float*)d_out;

    // Workspace layout (fixed offsets; pads cover the 1-deep prefetch
    // overrun: <=16 tiles = 32 KB past xbA, ~1 KB past xxh):
    //   xbA @ 0x000000: 625*128*16B = 1.28 MB (+pad)  -> ends < 0x150000
    //   xxf @ 0x150000: 40 KB raw norms
    //   xxh @ 0x160000: 40 KB (-0.5*norm) (+24 KB pad)
    //   wsK @ 0x170000: N*NSPLIT*LK u32 = 5.12 MB
    const size_t oXB = 0;
    const size_t oXX = 0x150000;
    const size_t oXH = 0x160000;
    const size_t oWK = 0x170000;
    __bf16* xbA = (__bf16*)((char*)d_ws + oXB);
    float*  xxf = (float*)((char*)d_ws + oXX);
    float*  xxh = (float*)((char*)d_ws + oXH);
    u32*    wsK = (u32*)((char*)d_ws + oWK);

    const int prepThreads = NTILES * 2 * 64 + N;         // 90000
    prep<<<(prepThreads + 255) / 256, 256, 0, stream>>>(x, xbA, xxf, xxh, N);

    long long totalF4 = (long long)out_size / 16;        // 25e6 float4
    int f4PerB = (int)((totalF4 + NCOMP - 1) / NCOMP);   // 19779
    topk_zero_mfma<<<NCOMP, 256, 0, stream>>>(
        xbA, xxh, N, wsK, out, totalF4, f4PerB);

    rescore_scatter<<<NTILES, 64, 0, stream>>>(wsK, x, xxf, out, N);
}